// Round 11
// baseline (295.527 us; speedup 1.0000x reference)
//
#include <hip/hip_runtime.h>
#include <hip/hip_bf16.h>

// Problem constants
#define NT 4301   // total tokens
#define NP 4201   // patch tokens (use *_p weights)
#define NDET 100  // detection tokens (use *_d weights)
#define DMODEL 768
#define NHEAD 12
#define HD 64
#define LN_EPS 1e-5f
#define LOG2E 1.4426950408889634f
#define QSCALE (0.125f * LOG2E)   // attn scale folded with log2(e): softmax in exp2 domain
#define NTP 4352                  // padded token count (68*64)
#define NCHUNK 68                 // ceil(4301/64)
#define FRAGSZ 512                // elems per frag blob: 64 lanes x 8 bf16
#define CHUNKSZ 4096              // elems per (head,chunk): 8 frags x 512

typedef __hip_bfloat16 bf16;
typedef __attribute__((ext_vector_type(4))) float f32x4;
typedef __attribute__((ext_vector_type(8))) short frag8;  // 8 bf16 in 4 VGPRs

// ---------------------------------------------------------------------------
// One fused cast: x + 8 weight matrices fp32->bf16 into contiguous ws region
// ---------------------------------------------------------------------------
__global__ __launch_bounds__(256) void cast_all_kernel(
    const float* __restrict__ x,
    const float* __restrict__ w0, const float* __restrict__ w1,
    const float* __restrict__ w2, const float* __restrict__ w3,
    const float* __restrict__ w4, const float* __restrict__ w5,
    const float* __restrict__ w6, const float* __restrict__ w7,
    bf16* __restrict__ dst, int nx, int nw, int total) {
    int i4 = (blockIdx.x * 256 + threadIdx.x) * 4;
    if (i4 >= total) return;
    const float* s;
    int off;
    if (i4 < nx) {
        s = x; off = i4;
    } else {
        int r = i4 - nx;
        int w = r / nw;
        off = r - w * nw;
        s = w0;
        if (w == 1) s = w1; else if (w == 2) s = w2; else if (w == 3) s = w3;
        else if (w == 4) s = w4; else if (w == 5) s = w5;
        else if (w == 6) s = w6; else if (w == 7) s = w7;
    }
    float4 v = *(const float4*)(s + off);
    bf16 o[4] = {__float2bfloat16(v.x), __float2bfloat16(v.y),
                 __float2bfloat16(v.z), __float2bfloat16(v.w)};
    *(ushort4*)(dst + i4) = *(ushort4*)o;
}

// ---------------------------------------------------------------------------
// Fused QKV v2: one block per (row-tile, head) computes Q, K, V together.
// grid = (68, 12). Per k-iter: stage As[64][32] + Bs[192][32] (wq|wk|wv rows)
// once; wave w computes 64 rows x 48 logical cols (12 MFMA per 7 ds_read_b128).
// Outputs: Q*QSCALE row-major; K/V pre-swizzled into MFMA B-frag order.
// ---------------------------------------------------------------------------
__global__ __launch_bounds__(256, 4) void qkv_kernel(
    const bf16* __restrict__ xb, const bf16* __restrict__ wbase,
    const float* __restrict__ bq_p, const float* __restrict__ bq_d,
    const float* __restrict__ bv_p, const float* __restrict__ bv_d,
    bf16* __restrict__ Qb, bf16* __restrict__ Ksw, bf16* __restrict__ Vsw) {
    __shared__ bf16 As[64][32];
    __shared__ bf16 Bs[192][32];   // rows 0-63: wq, 64-127: wk, 128-191: wv

    const int tid = threadIdx.x;
    const int wave = tid >> 6, lane = tid & 63;
    const int quad = lane >> 4, l16 = lane & 15;
    const int bx = blockIdx.x;
    const int h = blockIdx.y;
    const int is_det = bx >= 66;
    const int row0 = is_det ? NP + (bx - 66) * 64 : bx * 64;
    const int Mlim = is_det ? NT : NP;
    const int col0 = h * 64;
    const size_t nw = (size_t)DMODEL * DMODEL;
    const bf16* W = wbase + (is_det ? 3 * nw : 0);

    const f32x4 z4 = {0.f, 0.f, 0.f, 0.f};
    f32x4 acc[4][3];
#pragma unroll
    for (int r4 = 0; r4 < 4; ++r4)
#pragma unroll
        for (int f = 0; f < 3; ++f) acc[r4][f] = z4;

    const int srow = tid >> 2;          // 0..63
    const int scol8 = (tid & 3) * 8;    // 0,8,16,24
    int a_r = row0 + srow;
    if (a_r >= Mlim) a_r = Mlim - 1;
    const bf16* ap = xb + (size_t)a_r * DMODEL + scol8;
    const bf16* bp = W + (size_t)(col0 + srow) * DMODEL + scol8;

    uint4 areg  = *(const uint4*)(ap);
    uint4 breg0 = *(const uint4*)(bp);
    uint4 breg1 = *(const uint4*)(bp + nw);
    uint4 breg2 = *(const uint4*)(bp + 2 * nw);

    for (int k0 = 0; k0 < DMODEL; k0 += 32) {
        __syncthreads();
        *(uint4*)(&As[srow][scol8]) = areg;
        *(uint4*)(&Bs[srow][scol8]) = breg0;
        *(uint4*)(&Bs[64 + srow][scol8]) = breg1;
        *(uint4*)(&Bs[128 + srow][scol8]) = breg2;
        if (k0 + 32 < DMODEL) {
            areg  = *(const uint4*)(ap + k0 + 32);
            breg0 = *(const uint4*)(bp + k0 + 32);
            breg1 = *(const uint4*)(bp + nw + k0 + 32);
            breg2 = *(const uint4*)(bp + 2 * nw + k0 + 32);
        }
        __asm__ volatile("s_waitcnt lgkmcnt(0)" ::: "memory");
        __builtin_amdgcn_s_barrier();   // prefetch vmcnt stays in flight
        __asm__ volatile("" ::: "memory");
        frag8 af[4], bfr[3];
#pragma unroll
        for (int r4 = 0; r4 < 4; ++r4)
            af[r4] = *(const frag8*)(&As[r4 * 16 + l16][quad * 8]);
#pragma unroll
        for (int f = 0; f < 3; ++f)
            bfr[f] = *(const frag8*)(&Bs[wave * 48 + f * 16 + l16][quad * 8]);
#pragma unroll
        for (int r4 = 0; r4 < 4; ++r4)
#pragma unroll
            for (int f = 0; f < 3; ++f)
                acc[r4][f] = __builtin_amdgcn_mfma_f32_16x16x32_bf16(af[r4], bfr[f], acc[r4][f], 0, 0, 0);
        __asm__ volatile("" ::: "memory");
    }

    // epilogue: wave w covers logical cols [w*48, w*48+48); 16-col group oc=3w+f
#pragma unroll
    for (int f = 0; f < 3; ++f) {
        const int oc = 3 * wave + f;          // 0..11
        const int opi = oc >> 2;              // 0=Q 1=K 2=V
        const int cin = (oc & 3) * 16 + l16;  // head-dim 0..63
        const int c = col0 + cin;             // global dim
        float bv = 0.f, scale = 1.f;
        if (opi == 0) { bv = (is_det ? bq_d : bq_p)[c]; scale = QSCALE; }
        else if (opi == 2) { bv = (is_det ? bv_d : bv_p)[c]; }
#pragma unroll
        for (int r4 = 0; r4 < 4; ++r4) {
#pragma unroll
            for (int j = 0; j < 4; ++j) {
                const int r = row0 + r4 * 16 + quad * 4 + j;
                if (r >= Mlim) continue;
                const bf16 val = __float2bfloat16((acc[r4][f][j] + bv) * scale);
                if (opi == 0) {
                    Qb[(size_t)r * DMODEL + c] = val;
                } else if (opi == 1) {
                    const int cc = r >> 6, tf = (r >> 4) & 3, ln = r & 15;
                    const int s = cin >> 5, qd = (cin >> 3) & 3, je = cin & 7;
                    Ksw[((size_t)(h * NCHUNK + cc) * 8 + tf * 2 + s) * FRAGSZ +
                        (qd * 16 + ln) * 8 + je] = val;
                } else {
                    const int t = cin >> 4, le = cin & 15;
                    const int cc = r >> 6, rr = r & 63;
                    const int sv = rr >> 5, qv = (rr >> 3) & 3, je = rr & 7;
                    Vsw[((size_t)(h * NCHUNK + cc) * 8 + t * 2 + sv) * FRAGSZ +
                        (qv * 16 + le) * 8 + je] = val;
                }
            }
        }
    }
}

// ---------------------------------------------------------------------------
// Flash attention v7: cross-chunk stage pipelining.
// S(c) is computed in iteration c-1 (or prologue). Each iteration:
//   exp(S(c)) -> Ps  [VALU+DS]   overlapped with   S <- QK(c+1)  [MFMA]
//   (S registers reused: dead after exp), kf rotates to c+2 (in flight a full
//   iter), PV(c) [MFMA], vf rotates to c+1. MFMA and VALU pipes co-schedule
//   (m114), breaking the serial QK->exp->Ps->PV chain of v6.
// Barrier-free, frag-order global K/V, kv-split partials.
// ---------------------------------------------------------------------------
__global__ __launch_bounds__(256, 4) void attn_kernel(
    const bf16* __restrict__ Q, const bf16* __restrict__ Ksw,
    const bf16* __restrict__ Vsw, float* __restrict__ O_part,
    float* __restrict__ l_part, int cpb) {
    __shared__ bf16 Ps[4][16][72];   // per-wave P tile (C->A transpose)

    const int tid = threadIdx.x;
    const int wave = tid >> 6, lane = tid & 63;
    const int quad = lane >> 4, l16 = lane & 15;
    const int h = blockIdx.y;
    const int z = blockIdx.z;
    const int qbase = blockIdx.x * 64;
    const int hoff = h * HD;
    const int c0 = z * cpb, c1 = c0 + cpb;

    frag8 ones;
#pragma unroll
    for (int j = 0; j < 8; ++j) ones[j] = (short)0x3F80;

    // Q fragments direct from global: A[m=l16][k=quad*8+j]
    int qr = qbase + wave * 16 + l16;
    if (qr >= NT) qr = NT - 1;
    frag8 qf0 = *(const frag8*)(Q + (size_t)qr * DMODEL + hoff + quad * 8);
    frag8 qf1 = *(const frag8*)(Q + (size_t)qr * DMODEL + hoff + 32 + quad * 8);

    const bf16* kb0 = Ksw + (size_t)h * NCHUNK * CHUNKSZ + lane * 8;
    const bf16* vb0 = Vsw + (size_t)h * NCHUNK * CHUNKSZ + lane * 8;

    // ---- prologue: S = QK(c0); kf <- c0+1; vf <- c0
    frag8 kf[8], vf[8];
#pragma unroll
    for (int f = 0; f < 8; ++f)
        kf[f] = *(const frag8*)(kb0 + (size_t)c0 * CHUNKSZ + f * FRAGSZ);

    f32x4 S[4] = {{0.f,0.f,0.f,0.f},{0.f,0.f,0.f,0.f},{0.f,0.f,0.f,0.f},{0.f,0.f,0.f,0.f}};
#pragma unroll
    for (int t = 0; t < 4; ++t) {
        S[t] = __builtin_amdgcn_mfma_f32_16x16x32_bf16(qf0, kf[t * 2 + 0], S[t], 0, 0, 0);
        S[t] = __builtin_amdgcn_mfma_f32_16x16x32_bf16(qf1, kf[t * 2 + 1], S[t], 0, 0, 0);
    }
    if (c0 + 1 < c1) {
#pragma unroll
        for (int f = 0; f < 8; ++f)
            kf[f] = *(const frag8*)(kb0 + (size_t)(c0 + 1) * CHUNKSZ + f * FRAGSZ);
    }
#pragma unroll
    for (int f = 0; f < 8; ++f)
        vf[f] = *(const frag8*)(vb0 + (size_t)c0 * CHUNKSZ + f * FRAGSZ);
    __asm__ volatile("" ::: "memory");

    f32x4 accO[4] = {{0.f,0.f,0.f,0.f},{0.f,0.f,0.f,0.f},{0.f,0.f,0.f,0.f},{0.f,0.f,0.f,0.f}};
    f32x4 accL = {0.f, 0.f, 0.f, 0.f};

    for (int c = c0; c < c1; ++c) {
        if (c == NCHUNK - 1) {
            const int kbase = c * 64;
#pragma unroll
            for (int t = 0; t < 4; ++t)
                if (kbase + t * 16 + l16 >= NT)
                    S[t][0] = S[t][1] = S[t][2] = S[t][3] = -1e30f;
        }
        // exp(S(c)) -> Ps  [VALU+DS]; S becomes dead
#pragma unroll
        for (int t = 0; t < 4; ++t)
#pragma unroll
            for (int j = 0; j < 4; ++j)
                Ps[wave][quad * 4 + j][t * 16 + l16] =
                    __float2bfloat16(__builtin_exp2f(S[t][j]));
        // S <- QK(c+1)  [MFMA] -- independent of exp; pipes co-schedule
        if (c + 1 < c1) {
#pragma unroll
            for (int t = 0; t < 4; ++t) {
                f32x4 sn = {0.f, 0.f, 0.f, 0.f};
                sn = __builtin_amdgcn_mfma_f32_16x16x32_bf16(qf0, kf[t * 2 + 0], sn, 0, 0, 0);
                sn = __builtin_amdgcn_mfma_f32_16x16x32_bf16(qf1, kf[t * 2 + 1], sn, 0, 0, 0);
                S[t] = sn;
            }
        }
        // rotate kf to c+2: full iteration of flight time
        if (c + 2 < c1) {
#pragma unroll
            for (int f = 0; f < 8; ++f)
                kf[f] = *(const frag8*)(kb0 + (size_t)(c + 2) * CHUNKSZ + f * FRAGSZ);
        }
        __asm__ volatile("" ::: "memory");   // pin kf loads before PV
        // PV(c): O += P @ V ; l += P @ ones  (lgkm wait on Ps auto-inserted)
#pragma unroll
        for (int s = 0; s < 2; ++s) {
            frag8 pf = *(const frag8*)(&Ps[wave][l16][s * 32 + quad * 8]);
            accL = __builtin_amdgcn_mfma_f32_16x16x32_bf16(pf, ones, accL, 0, 0, 0);
#pragma unroll
            for (int t = 0; t < 4; ++t)
                accO[t] = __builtin_amdgcn_mfma_f32_16x16x32_bf16(pf, vf[t * 2 + s], accO[t], 0, 0, 0);
        }
        // rotate vf to c+1: in flight across next iter's exp/QK
        if (c + 1 < c1) {
#pragma unroll
            for (int f = 0; f < 8; ++f)
                vf[f] = *(const frag8*)(vb0 + (size_t)(c + 1) * CHUNKSZ + f * FRAGSZ);
        }
        __asm__ volatile("" ::: "memory");
    }

    // write fp32 partials (no normalization here)
    float* Op = O_part + (size_t)z * NT * DMODEL;
#pragma unroll
    for (int j = 0; j < 4; ++j) {
        const int r = qbase + wave * 16 + quad * 4 + j;
        if (r < NT) {
#pragma unroll
            for (int t = 0; t < 4; ++t)
                Op[(size_t)r * DMODEL + hoff + t * 16 + l16] = accO[t][j];
            if (l16 == 0)
                l_part[((size_t)z * NHEAD + h) * NTP + r] = accL[j];
        }
    }
}

// ---------------------------------------------------------------------------
// Reduce kv-splits + per-head normalize + LayerNorm. grid = (NT), 256 thr.
// ---------------------------------------------------------------------------
__global__ __launch_bounds__(256) void reduce_ln_kernel(
    const float* __restrict__ O_part, const float* __restrict__ l_part,
    const float* __restrict__ g, const float* __restrict__ b,
    bf16* __restrict__ out, int nsplit) {
    const int n = blockIdx.x;
    const int tid = threadIdx.x;
    float vals[3];
#pragma unroll
    for (int i = 0; i < 3; ++i) {
        const int d = tid + i * 256;
        const int hh = d >> 6;
        float o = 0.f, lv = 0.f;
        for (int s = 0; s < nsplit; ++s) {
            o  += O_part[((size_t)s * NT + n) * DMODEL + d];
            lv += l_part[((size_t)s * NHEAD + hh) * NTP + n];
        }
        vals[i] = o / lv;
    }
    float s = vals[0] + vals[1] + vals[2];
    float s2 = vals[0] * vals[0] + vals[1] * vals[1] + vals[2] * vals[2];
#pragma unroll
    for (int off = 1; off < 64; off <<= 1) {
        s += __shfl_xor(s, off);
        s2 += __shfl_xor(s2, off);
    }
    __shared__ float ss[4], ss2[4];
    const int wave = tid >> 6, lane = tid & 63;
    if (lane == 0) { ss[wave] = s; ss2[wave] = s2; }
    __syncthreads();
    s = ss[0] + ss[1] + ss[2] + ss[3];
    s2 = ss2[0] + ss2[1] + ss2[2] + ss2[3];
    const float mu = s * (1.0f / 768.0f);
    float var = s2 * (1.0f / 768.0f) - mu * mu;
    const float inv = rsqrtf(var + LN_EPS);
#pragma unroll
    for (int i = 0; i < 3; ++i) {
        const int d = tid + i * 256;
        const float v = (vals[i] - mu) * inv * g[d] + b[d];
        out[(size_t)n * DMODEL + d] = __float2bfloat16(v);
    }
}

// ---------------------------------------------------------------------------
// Output projection, region-select. grid = (68, 12). fp32 out.
// ---------------------------------------------------------------------------
__global__ __launch_bounds__(256) void out_kernel(
    const bf16* __restrict__ Lb, const bf16* __restrict__ wo,
    const float* __restrict__ bo_p, const float* __restrict__ bo_d,
    float* __restrict__ out) {
    __shared__ bf16 As[64][32];
    __shared__ bf16 Bs[64][32];

    const int tid = threadIdx.x;
    const int wave = tid >> 6, lane = tid & 63;
    const int quad = lane >> 4, l16 = lane & 15;
    const int bx = blockIdx.x;
    const int is_det = bx >= 66;
    const int row0 = is_det ? NP + (bx - 66) * 64 : bx * 64;
    const int Mlim = is_det ? NT : NP;
    const int col0 = blockIdx.y * 64;
    const size_t nw = (size_t)DMODEL * DMODEL;
    const bf16* B = wo + (is_det ? nw : 0);
    const float* bias = is_det ? bo_d : bo_p;

    f32x4 acc[4] = {{0.f,0.f,0.f,0.f},{0.f,0.f,0.f,0.f},{0.f,0.f,0.f,0.f},{0.f,0.f,0.f,0.f}};

    const int arow = tid >> 2;
    const int acol = (tid & 3) * 8;
    int a_r = row0 + arow;
    if (a_r >= Mlim) a_r = Mlim - 1;
    const bf16* ap = Lb + (size_t)a_r * DMODEL + acol;
    const bf16* bp = B + (size_t)(col0 + arow) * DMODEL + acol;

    uint4 areg = *(const uint4*)(ap);
    uint4 breg = *(const uint4*)(bp);

    for (int k0 = 0; k0 < DMODEL; k0 += 32) {
        __syncthreads();
        *(uint4*)(&As[arow][acol]) = areg;
        *(uint4*)(&Bs[arow][acol]) = breg;
        if (k0 + 32 < DMODEL) {
            areg = *(const uint4*)(ap + k0 + 32);
            breg = *(const uint4*)(bp + k0 + 32);
        }
        __asm__ volatile("s_waitcnt lgkmcnt(0)" ::: "memory");
        __builtin_amdgcn_s_barrier();
        __asm__ volatile("" ::: "memory");
        frag8 af = *(const frag8*)(&As[wave * 16 + l16][quad * 8]);
#pragma unroll
        for (int t = 0; t < 4; ++t) {
            frag8 bfq = *(const frag8*)(&Bs[t * 16 + l16][quad * 8]);
            acc[t] = __builtin_amdgcn_mfma_f32_16x16x32_bf16(af, bfq, acc[t], 0, 0, 0);
        }
        __asm__ volatile("" ::: "memory");
    }

    const int rbase = row0 + wave * 16 + quad * 4;
#pragma unroll
    for (int t = 0; t < 4; ++t) {
        const int c = col0 + t * 16 + l16;
        const float bv = bias[c];
#pragma unroll
        for (int j = 0; j < 4; ++j) {
            const int r = rbase + j;
            if (r < Mlim) out[(size_t)r * DMODEL + c] = acc[t][j] + bv;
        }
    }
}

// ---------------------------------------------------------------------------
extern "C" void kernel_launch(void* const* d_in, const int* in_sizes, int n_in,
                              void* d_out, int out_size, void* d_ws, size_t ws_size,
                              hipStream_t stream) {
    const float* x    = (const float*)d_in[0];
    const float* wq_p = (const float*)d_in[1];
    const float* wk_p = (const float*)d_in[2];
    const float* wv_p = (const float*)d_in[3];
    const float* wq_d = (const float*)d_in[4];
    const float* wk_d = (const float*)d_in[5];
    const float* wv_d = (const float*)d_in[6];
    const float* bq_p = (const float*)d_in[7];
    const float* bv_p = (const float*)d_in[8];
    const float* bq_d = (const float*)d_in[9];
    const float* bv_d = (const float*)d_in[10];
    const float* ln_g = (const float*)d_in[11];
    const float* ln_b = (const float*)d_in[12];
    const float* wo_p = (const float*)d_in[13];
    const float* bo_p = (const float*)d_in[14];
    const float* wo_d = (const float*)d_in[15];
    const float* bo_d = (const float*)d_in[16];
    float* out = (float*)d_out;

    const size_t nx  = (size_t)NT * DMODEL;       // 3,303,168
    const size_t nsw = (size_t)NHEAD * NCHUNK * CHUNKSZ;  // 3,342,336
    const size_t nw  = (size_t)DMODEL * DMODEL;   // 589,824

    // fixed region
    char* ws = (char*)d_ws;
    bf16* xb   = (bf16*)ws; ws += nx * 2;         // reused as Lb after qkv
    bf16* wqkv = (bf16*)ws; ws += 6 * nw * 2;
    bf16* wob  = (bf16*)ws; ws += 2 * nw * 2;
    bf16* Qb   = (bf16*)ws; ws += nx * 2;
    bf16* Ksw  = (bf16*)ws; ws += nsw * 2;
    bf16* Vsw  = (bf16*)ws; ws += nsw * 2;
    const size_t fixed = (size_t)(ws - (char*)d_ws);

    // per-split region: O_part (fp32 NT x 768) + l_part (fp32 12 x NTP)
    const size_t per_split = nx * 4 + (size_t)NHEAD * NTP * 4;
    int nsplit = 1;
    if (ws_size >= fixed + 4 * per_split) nsplit = 4;
    else if (ws_size >= fixed + 2 * per_split) nsplit = 2;
    const int cpb = NCHUNK / nsplit;              // 68 divisible by 1/2/4

    float* O_part = (float*)ws;
    float* l_part = (float*)(ws + (size_t)nsplit * nx * 4);
    bf16* Lb = xb;   // xb dead after qkv_kernel

    const int total = (int)(nx + 8 * nw);
    cast_all_kernel<<<dim3((total / 4 + 255) / 256), dim3(256), 0, stream>>>(
        x, wq_p, wk_p, wv_p, wq_d, wk_d, wv_d, wo_p, wo_d, xb, (int)nx, (int)nw, total);

    qkv_kernel<<<dim3(68, 12), dim3(256), 0, stream>>>(
        xb, wqkv, bq_p, bq_d, bv_p, bv_d, Qb, Ksw, Vsw);

    attn_kernel<<<dim3(NCHUNK, NHEAD, nsplit), dim3(256), 0, stream>>>(
        Qb, Ksw, Vsw, O_part, l_part, cpb);

    reduce_ln_kernel<<<dim3(NT), dim3(256), 0, stream>>>(
        O_part, l_part, ln_g, ln_b, Lb, nsplit);

    out_kernel<<<dim3(68, 12), dim3(256), 0, stream>>>(Lb, wob, bo_p, bo_d, out);
}

// Round 12
// 276.998 us; speedup vs baseline: 1.0669x; 1.0669x over previous
//
#include <hip/hip_runtime.h>
#include <hip/hip_bf16.h>

// Problem constants
#define NT 4301   // total tokens
#define NP 4201   // patch tokens (use *_p weights)
#define NDET 100  // detection tokens (use *_d weights)
#define DMODEL 768
#define NHEAD 12
#define HD 64
#define LN_EPS 1e-5f
#define LOG2E 1.4426950408889634f
#define QSCALE (0.125f * LOG2E)   // attn scale folded with log2(e): softmax in exp2 domain
#define NTP 4352                  // padded token count (68*64 = 34*128)
#define NCHUNK 68                 // ceil(4301/64)
#define FRAGSZ 512                // elems per frag blob: 64 lanes x 8 bf16
#define CHUNKSZ 4096              // elems per (head,chunk): 8 frags x 512

typedef __hip_bfloat16 bf16;
typedef __attribute__((ext_vector_type(4))) float f32x4;
typedef __attribute__((ext_vector_type(8))) short frag8;  // 8 bf16 in 4 VGPRs

// fast RNE fp32->bf16 (no NaN path; inputs are exp2 outputs / finite)
__device__ __forceinline__ unsigned short fast_bf16(float x) {
    unsigned int u = __float_as_uint(x);
    u += 0x7FFFu + ((u >> 16) & 1u);
    return (unsigned short)(u >> 16);
}

// ---------------------------------------------------------------------------
// One fused cast: x + 8 weight matrices fp32->bf16 into contiguous ws region
// ---------------------------------------------------------------------------
__global__ __launch_bounds__(256) void cast_all_kernel(
    const float* __restrict__ x,
    const float* __restrict__ w0, const float* __restrict__ w1,
    const float* __restrict__ w2, const float* __restrict__ w3,
    const float* __restrict__ w4, const float* __restrict__ w5,
    const float* __restrict__ w6, const float* __restrict__ w7,
    bf16* __restrict__ dst, int nx, int nw, int total) {
    int i4 = (blockIdx.x * 256 + threadIdx.x) * 4;
    if (i4 >= total) return;
    const float* s;
    int off;
    if (i4 < nx) {
        s = x; off = i4;
    } else {
        int r = i4 - nx;
        int w = r / nw;
        off = r - w * nw;
        s = w0;
        if (w == 1) s = w1; else if (w == 2) s = w2; else if (w == 3) s = w3;
        else if (w == 4) s = w4; else if (w == 5) s = w5;
        else if (w == 6) s = w6; else if (w == 7) s = w7;
    }
    float4 v = *(const float4*)(s + off);
    bf16 o[4] = {__float2bfloat16(v.x), __float2bfloat16(v.y),
                 __float2bfloat16(v.z), __float2bfloat16(v.w)};
    *(ushort4*)(dst + i4) = *(ushort4*)o;
}

// ---------------------------------------------------------------------------
// Fused QKV v2: one block per (row-tile, head) computes Q, K, V together.
// grid = (68, 12). Outputs: Q*QSCALE row-major; K/V pre-swizzled frag order.
// ---------------------------------------------------------------------------
__global__ __launch_bounds__(256, 4) void qkv_kernel(
    const bf16* __restrict__ xb, const bf16* __restrict__ wbase,
    const float* __restrict__ bq_p, const float* __restrict__ bq_d,
    const float* __restrict__ bv_p, const float* __restrict__ bv_d,
    bf16* __restrict__ Qb, bf16* __restrict__ Ksw, bf16* __restrict__ Vsw) {
    __shared__ bf16 As[64][32];
    __shared__ bf16 Bs[192][32];   // rows 0-63: wq, 64-127: wk, 128-191: wv

    const int tid = threadIdx.x;
    const int wave = tid >> 6, lane = tid & 63;
    const int quad = lane >> 4, l16 = lane & 15;
    const int bx = blockIdx.x;
    const int h = blockIdx.y;
    const int is_det = bx >= 66;
    const int row0 = is_det ? NP + (bx - 66) * 64 : bx * 64;
    const int Mlim = is_det ? NT : NP;
    const int col0 = h * 64;
    const size_t nw = (size_t)DMODEL * DMODEL;
    const bf16* W = wbase + (is_det ? 3 * nw : 0);

    const f32x4 z4 = {0.f, 0.f, 0.f, 0.f};
    f32x4 acc[4][3];
#pragma unroll
    for (int r4 = 0; r4 < 4; ++r4)
#pragma unroll
        for (int f = 0; f < 3; ++f) acc[r4][f] = z4;

    const int srow = tid >> 2;          // 0..63
    const int scol8 = (tid & 3) * 8;    // 0,8,16,24
    int a_r = row0 + srow;
    if (a_r >= Mlim) a_r = Mlim - 1;
    const bf16* ap = xb + (size_t)a_r * DMODEL + scol8;
    const bf16* bp = W + (size_t)(col0 + srow) * DMODEL + scol8;

    uint4 areg  = *(const uint4*)(ap);
    uint4 breg0 = *(const uint4*)(bp);
    uint4 breg1 = *(const uint4*)(bp + nw);
    uint4 breg2 = *(const uint4*)(bp + 2 * nw);

    for (int k0 = 0; k0 < DMODEL; k0 += 32) {
        __syncthreads();
        *(uint4*)(&As[srow][scol8]) = areg;
        *(uint4*)(&Bs[srow][scol8]) = breg0;
        *(uint4*)(&Bs[64 + srow][scol8]) = breg1;
        *(uint4*)(&Bs[128 + srow][scol8]) = breg2;
        if (k0 + 32 < DMODEL) {
            areg  = *(const uint4*)(ap + k0 + 32);
            breg0 = *(const uint4*)(bp + k0 + 32);
            breg1 = *(const uint4*)(bp + nw + k0 + 32);
            breg2 = *(const uint4*)(bp + 2 * nw + k0 + 32);
        }
        __asm__ volatile("s_waitcnt lgkmcnt(0)" ::: "memory");
        __builtin_amdgcn_s_barrier();   // prefetch vmcnt stays in flight
        __asm__ volatile("" ::: "memory");
        frag8 af[4], bfr[3];
#pragma unroll
        for (int r4 = 0; r4 < 4; ++r4)
            af[r4] = *(const frag8*)(&As[r4 * 16 + l16][quad * 8]);
#pragma unroll
        for (int f = 0; f < 3; ++f)
            bfr[f] = *(const frag8*)(&Bs[wave * 48 + f * 16 + l16][quad * 8]);
#pragma unroll
        for (int r4 = 0; r4 < 4; ++r4)
#pragma unroll
            for (int f = 0; f < 3; ++f)
                acc[r4][f] = __builtin_amdgcn_mfma_f32_16x16x32_bf16(af[r4], bfr[f], acc[r4][f], 0, 0, 0);
        __asm__ volatile("" ::: "memory");
    }

    // epilogue: wave w covers logical cols [w*48, w*48+48); 16-col group oc=3w+f
#pragma unroll
    for (int f = 0; f < 3; ++f) {
        const int oc = 3 * wave + f;          // 0..11
        const int opi = oc >> 2;              // 0=Q 1=K 2=V
        const int cin = (oc & 3) * 16 + l16;  // head-dim 0..63
        const int c = col0 + cin;             // global dim
        float bv = 0.f, scale = 1.f;
        if (opi == 0) { bv = (is_det ? bq_d : bq_p)[c]; scale = QSCALE; }
        else if (opi == 2) { bv = (is_det ? bv_d : bv_p)[c]; }
#pragma unroll
        for (int r4 = 0; r4 < 4; ++r4) {
#pragma unroll
            for (int j = 0; j < 4; ++j) {
                const int r = row0 + r4 * 16 + quad * 4 + j;
                if (r >= Mlim) continue;
                const bf16 val = __float2bfloat16((acc[r4][f][j] + bv) * scale);
                if (opi == 0) {
                    Qb[(size_t)r * DMODEL + c] = val;
                } else if (opi == 1) {
                    const int cc = r >> 6, tf = (r >> 4) & 3, ln = r & 15;
                    const int s = cin >> 5, qd = (cin >> 3) & 3, je = cin & 7;
                    Ksw[((size_t)(h * NCHUNK + cc) * 8 + tf * 2 + s) * FRAGSZ +
                        (qd * 16 + ln) * 8 + je] = val;
                } else {
                    const int t = cin >> 4, le = cin & 15;
                    const int cc = r >> 6, rr = r & 63;
                    const int sv = rr >> 5, qv = (rr >> 3) & 3, je = rr & 7;
                    Vsw[((size_t)(h * NCHUNK + cc) * 8 + t * 2 + sv) * FRAGSZ +
                        (qv * 16 + le) * 8 + je] = val;
                }
            }
        }
    }
}

// ---------------------------------------------------------------------------
// Flash attention v8: 32 q-rows per wave (128-row blocks) -- each K/V frag
// feeds 2 MFMAs instead of 1, halving VMEM return bytes per FLOP (the R11
// binder). grid = (34, 12, nsplit). Barrier-free; frag-order global K/V;
// wave-private LDS P transpose; fast RNE bf16 (no NaN path) for P.
// ---------------------------------------------------------------------------
__global__ __launch_bounds__(256, 2) void attn_kernel(
    const bf16* __restrict__ Q, const bf16* __restrict__ Ksw,
    const bf16* __restrict__ Vsw, float* __restrict__ O_part,
    float* __restrict__ l_part, int cpb) {
    __shared__ unsigned short Ps[4][32][72];   // per-wave 32-row P tile

    const int tid = threadIdx.x;
    const int wave = tid >> 6, lane = tid & 63;
    const int quad = lane >> 4, l16 = lane & 15;
    const int h = blockIdx.y;
    const int z = blockIdx.z;
    const int qbase = blockIdx.x * 128;
    const int hoff = h * HD;
    const int c0 = z * cpb, c1 = c0 + cpb;

    frag8 ones;
#pragma unroll
    for (int j = 0; j < 8; ++j) ones[j] = (short)0x3F80;

    // Q fragments for 2 row-groups: rows qbase + wave*32 + g*16 + l16
    frag8 qf[2][2];
#pragma unroll
    for (int g = 0; g < 2; ++g) {
        int qr = qbase + wave * 32 + g * 16 + l16;
        if (qr >= NT) qr = NT - 1;
#pragma unroll
        for (int s = 0; s < 2; ++s)
            qf[g][s] = *(const frag8*)(Q + (size_t)qr * DMODEL + hoff + s * 32 + quad * 8);
    }

    const bf16* kb0 = Ksw + (size_t)h * NCHUNK * CHUNKSZ + lane * 8;
    const bf16* vb0 = Vsw + (size_t)h * NCHUNK * CHUNKSZ + lane * 8;

    const f32x4 z4 = {0.f, 0.f, 0.f, 0.f};
    f32x4 accO[2][4], accL[2];
#pragma unroll
    for (int g = 0; g < 2; ++g) {
        accL[g] = z4;
#pragma unroll
        for (int t = 0; t < 4; ++t) accO[g][t] = z4;
    }

    for (int c = c0; c < c1; ++c) {
        const bf16* kc = kb0 + (size_t)c * CHUNKSZ;
        const bf16* vc = vb0 + (size_t)c * CHUNKSZ;
        frag8 kf[8], vf[8];
#pragma unroll
        for (int f = 0; f < 8; ++f) {
            kf[f] = *(const frag8*)(kc + f * FRAGSZ);
            vf[f] = *(const frag8*)(vc + f * FRAGSZ);
        }

        // S = Q @ K^T for both row-groups (16 MFMA per 8 kf frags)
        f32x4 S[2][4];
#pragma unroll
        for (int g = 0; g < 2; ++g)
#pragma unroll
            for (int t = 0; t < 4; ++t) {
                f32x4 s0 = __builtin_amdgcn_mfma_f32_16x16x32_bf16(qf[g][0], kf[t * 2 + 0], z4, 0, 0, 0);
                S[g][t]  = __builtin_amdgcn_mfma_f32_16x16x32_bf16(qf[g][1], kf[t * 2 + 1], s0, 0, 0, 0);
            }
        if (c == NCHUNK - 1) {
            const int kbase = c * 64;
#pragma unroll
            for (int t = 0; t < 4; ++t)
                if (kbase + t * 16 + l16 >= NT)
#pragma unroll
                    for (int g = 0; g < 2; ++g)
                        S[g][t][0] = S[g][t][1] = S[g][t][2] = S[g][t][3] = -1e30f;
        }
        // p = exp2(s) -> wave-private LDS (fast RNE bf16, no NaN path)
#pragma unroll
        for (int g = 0; g < 2; ++g)
#pragma unroll
            for (int t = 0; t < 4; ++t)
#pragma unroll
                for (int j = 0; j < 4; ++j)
                    Ps[wave][g * 16 + quad * 4 + j][t * 16 + l16] =
                        fast_bf16(__builtin_exp2f(S[g][t][j]));
        __asm__ volatile("" ::: "memory");   // same-wave DS in-order
        // O += P @ V ; l += P @ ones  (20 MFMA per 8 vf frags)
#pragma unroll
        for (int s = 0; s < 2; ++s)
#pragma unroll
            for (int g = 0; g < 2; ++g) {
                frag8 pf = *(const frag8*)(&Ps[wave][g * 16 + l16][s * 32 + quad * 8]);
                accL[g] = __builtin_amdgcn_mfma_f32_16x16x32_bf16(pf, ones, accL[g], 0, 0, 0);
#pragma unroll
                for (int t = 0; t < 4; ++t)
                    accO[g][t] = __builtin_amdgcn_mfma_f32_16x16x32_bf16(pf, vf[t * 2 + s], accO[g][t], 0, 0, 0);
            }
        __asm__ volatile("" ::: "memory");
    }

    // write fp32 partials
    float* Op = O_part + (size_t)z * NT * DMODEL;
#pragma unroll
    for (int g = 0; g < 2; ++g)
#pragma unroll
        for (int j = 0; j < 4; ++j) {
            const int r = qbase + wave * 32 + g * 16 + quad * 4 + j;
            if (r < NT) {
#pragma unroll
                for (int t = 0; t < 4; ++t)
                    Op[(size_t)r * DMODEL + hoff + t * 16 + l16] = accO[g][t][j];
                if (l16 == 0)
                    l_part[((size_t)z * NHEAD + h) * NTP + r] = accL[g][j];
            }
        }
}

// ---------------------------------------------------------------------------
// Reduce kv-splits + per-head normalize + LayerNorm. grid = (NT), 256 thr.
// ---------------------------------------------------------------------------
__global__ __launch_bounds__(256) void reduce_ln_kernel(
    const float* __restrict__ O_part, const float* __restrict__ l_part,
    const float* __restrict__ g, const float* __restrict__ b,
    bf16* __restrict__ out, int nsplit) {
    const int n = blockIdx.x;
    const int tid = threadIdx.x;
    float vals[3];
#pragma unroll
    for (int i = 0; i < 3; ++i) {
        const int d = tid + i * 256;
        const int hh = d >> 6;
        float o = 0.f, lv = 0.f;
        for (int s = 0; s < nsplit; ++s) {
            o  += O_part[((size_t)s * NT + n) * DMODEL + d];
            lv += l_part[((size_t)s * NHEAD + hh) * NTP + n];
        }
        vals[i] = o / lv;
    }
    float s = vals[0] + vals[1] + vals[2];
    float s2 = vals[0] * vals[0] + vals[1] * vals[1] + vals[2] * vals[2];
#pragma unroll
    for (int off = 1; off < 64; off <<= 1) {
        s += __shfl_xor(s, off);
        s2 += __shfl_xor(s2, off);
    }
    __shared__ float ss[4], ss2[4];
    const int wave = tid >> 6, lane = tid & 63;
    if (lane == 0) { ss[wave] = s; ss2[wave] = s2; }
    __syncthreads();
    s = ss[0] + ss[1] + ss[2] + ss[3];
    s2 = ss2[0] + ss2[1] + ss2[2] + ss2[3];
    const float mu = s * (1.0f / 768.0f);
    float var = s2 * (1.0f / 768.0f) - mu * mu;
    const float inv = rsqrtf(var + LN_EPS);
#pragma unroll
    for (int i = 0; i < 3; ++i) {
        const int d = tid + i * 256;
        const float v = (vals[i] - mu) * inv * g[d] + b[d];
        out[(size_t)n * DMODEL + d] = __float2bfloat16(v);
    }
}

// ---------------------------------------------------------------------------
// Output projection, region-select. grid = (68, 12). fp32 out.
// ---------------------------------------------------------------------------
__global__ __launch_bounds__(256) void out_kernel(
    const bf16* __restrict__ Lb, const bf16* __restrict__ wo,
    const float* __restrict__ bo_p, const float* __restrict__ bo_d,
    float* __restrict__ out) {
    __shared__ bf16 As[64][32];
    __shared__ bf16 Bs[64][32];

    const int tid = threadIdx.x;
    const int wave = tid >> 6, lane = tid & 63;
    const int quad = lane >> 4, l16 = lane & 15;
    const int bx = blockIdx.x;
    const int is_det = bx >= 66;
    const int row0 = is_det ? NP + (bx - 66) * 64 : bx * 64;
    const int Mlim = is_det ? NT : NP;
    const int col0 = blockIdx.y * 64;
    const size_t nw = (size_t)DMODEL * DMODEL;
    const bf16* B = wo + (is_det ? nw : 0);
    const float* bias = is_det ? bo_d : bo_p;

    f32x4 acc[4] = {{0.f,0.f,0.f,0.f},{0.f,0.f,0.f,0.f},{0.f,0.f,0.f,0.f},{0.f,0.f,0.f,0.f}};

    const int arow = tid >> 2;
    const int acol = (tid & 3) * 8;
    int a_r = row0 + arow;
    if (a_r >= Mlim) a_r = Mlim - 1;
    const bf16* ap = Lb + (size_t)a_r * DMODEL + acol;
    const bf16* bp = B + (size_t)(col0 + arow) * DMODEL + acol;

    uint4 areg = *(const uint4*)(ap);
    uint4 breg = *(const uint4*)(bp);

    for (int k0 = 0; k0 < DMODEL; k0 += 32) {
        __syncthreads();
        *(uint4*)(&As[arow][acol]) = areg;
        *(uint4*)(&Bs[arow][acol]) = breg;
        if (k0 + 32 < DMODEL) {
            areg = *(const uint4*)(ap + k0 + 32);
            breg = *(const uint4*)(bp + k0 + 32);
        }
        __asm__ volatile("s_waitcnt lgkmcnt(0)" ::: "memory");
        __builtin_amdgcn_s_barrier();
        __asm__ volatile("" ::: "memory");
        frag8 af = *(const frag8*)(&As[wave * 16 + l16][quad * 8]);
#pragma unroll
        for (int t = 0; t < 4; ++t) {
            frag8 bfq = *(const frag8*)(&Bs[t * 16 + l16][quad * 8]);
            acc[t] = __builtin_amdgcn_mfma_f32_16x16x32_bf16(af, bfq, acc[t], 0, 0, 0);
        }
        __asm__ volatile("" ::: "memory");
    }

    const int rbase = row0 + wave * 16 + quad * 4;
#pragma unroll
    for (int t = 0; t < 4; ++t) {
        const int c = col0 + t * 16 + l16;
        const float bv = bias[c];
#pragma unroll
        for (int j = 0; j < 4; ++j) {
            const int r = rbase + j;
            if (r < Mlim) out[(size_t)r * DMODEL + c] = acc[t][j] + bv;
        }
    }
}

// ---------------------------------------------------------------------------
extern "C" void kernel_launch(void* const* d_in, const int* in_sizes, int n_in,
                              void* d_out, int out_size, void* d_ws, size_t ws_size,
                              hipStream_t stream) {
    const float* x    = (const float*)d_in[0];
    const float* wq_p = (const float*)d_in[1];
    const float* wk_p = (const float*)d_in[2];
    const float* wv_p = (const float*)d_in[3];
    const float* wq_d = (const float*)d_in[4];
    const float* wk_d = (const float*)d_in[5];
    const float* wv_d = (const float*)d_in[6];
    const float* bq_p = (const float*)d_in[7];
    const float* bv_p = (const float*)d_in[8];
    const float* bq_d = (const float*)d_in[9];
    const float* bv_d = (const float*)d_in[10];
    const float* ln_g = (const float*)d_in[11];
    const float* ln_b = (const float*)d_in[12];
    const float* wo_p = (const float*)d_in[13];
    const float* bo_p = (const float*)d_in[14];
    const float* wo_d = (const float*)d_in[15];
    const float* bo_d = (const float*)d_in[16];
    float* out = (float*)d_out;

    const size_t nx  = (size_t)NT * DMODEL;       // 3,303,168
    const size_t nsw = (size_t)NHEAD * NCHUNK * CHUNKSZ;  // 3,342,336
    const size_t nw  = (size_t)DMODEL * DMODEL;   // 589,824

    // fixed region
    char* ws = (char*)d_ws;
    bf16* xb   = (bf16*)ws; ws += nx * 2;         // reused as Lb after qkv
    bf16* wqkv = (bf16*)ws; ws += 6 * nw * 2;
    bf16* wob  = (bf16*)ws; ws += 2 * nw * 2;
    bf16* Qb   = (bf16*)ws; ws += nx * 2;
    bf16* Ksw  = (bf16*)ws; ws += nsw * 2;
    bf16* Vsw  = (bf16*)ws; ws += nsw * 2;
    const size_t fixed = (size_t)(ws - (char*)d_ws);

    // per-split region: O_part (fp32 NT x 768) + l_part (fp32 12 x NTP)
    const size_t per_split = nx * 4 + (size_t)NHEAD * NTP * 4;
    int nsplit = 1;
    if (ws_size >= fixed + 4 * per_split) nsplit = 4;
    else if (ws_size >= fixed + 2 * per_split) nsplit = 2;
    const int cpb = NCHUNK / nsplit;              // 68 divisible by 1/2/4

    float* O_part = (float*)ws;
    float* l_part = (float*)(ws + (size_t)nsplit * nx * 4);
    bf16* Lb = xb;   // xb dead after qkv_kernel

    const int total = (int)(nx + 8 * nw);
    cast_all_kernel<<<dim3((total / 4 + 255) / 256), dim3(256), 0, stream>>>(
        x, wq_p, wk_p, wv_p, wq_d, wk_d, wv_d, wo_p, wo_d, xb, (int)nx, (int)nw, total);

    qkv_kernel<<<dim3(68, 12), dim3(256), 0, stream>>>(
        xb, wqkv, bq_p, bq_d, bv_p, bv_d, Qb, Ksw, Vsw);

    attn_kernel<<<dim3(34, NHEAD, nsplit), dim3(256), 0, stream>>>(
        Qb, Ksw, Vsw, O_part, l_part, cpb);

    reduce_ln_kernel<<<dim3(NT), dim3(256), 0, stream>>>(
        O_part, l_part, ln_g, ln_b, Lb, nsplit);

    out_kernel<<<dim3(68, 12), dim3(256), 0, stream>>>(Lb, wob, bo_p, bo_d, out);
}

// Round 13
// 264.935 us; speedup vs baseline: 1.1155x; 1.0455x over previous
//
#include <hip/hip_runtime.h>
#include <hip/hip_bf16.h>

// Problem constants
#define NT 4301   // total tokens
#define NP 4201   // patch tokens (use *_p weights)
#define NDET 100  // detection tokens (use *_d weights)
#define DMODEL 768
#define NHEAD 12
#define HD 64
#define LN_EPS 1e-5f
#define LOG2E 1.4426950408889634f
#define QSCALE (0.125f * LOG2E)   // attn scale folded with log2(e): softmax in exp2 domain
#define NTP 4352                  // padded token count (68*64 = 34*128)
#define NCHUNK 68                 // ceil(4301/64)
#define FRAGSZ 512                // elems per frag blob: 64 lanes x 8 bf16
#define CHUNKSZ 4096              // elems per (head,chunk): 8 frags x 512

typedef __hip_bfloat16 bf16;
typedef __attribute__((ext_vector_type(4))) float f32x4;
typedef __attribute__((ext_vector_type(8))) short frag8;  // 8 bf16 in 4 VGPRs

// ---------------------------------------------------------------------------
// One fused cast: x + 8 weight matrices fp32->bf16 into contiguous ws region
// ---------------------------------------------------------------------------
__global__ __launch_bounds__(256) void cast_all_kernel(
    const float* __restrict__ x,
    const float* __restrict__ w0, const float* __restrict__ w1,
    const float* __restrict__ w2, const float* __restrict__ w3,
    const float* __restrict__ w4, const float* __restrict__ w5,
    const float* __restrict__ w6, const float* __restrict__ w7,
    bf16* __restrict__ dst, int nx, int nw, int total) {
    int i4 = (blockIdx.x * 256 + threadIdx.x) * 4;
    if (i4 >= total) return;
    const float* s;
    int off;
    if (i4 < nx) {
        s = x; off = i4;
    } else {
        int r = i4 - nx;
        int w = r / nw;
        off = r - w * nw;
        s = w0;
        if (w == 1) s = w1; else if (w == 2) s = w2; else if (w == 3) s = w3;
        else if (w == 4) s = w4; else if (w == 5) s = w5;
        else if (w == 6) s = w6; else if (w == 7) s = w7;
    }
    float4 v = *(const float4*)(s + off);
    bf16 o[4] = {__float2bfloat16(v.x), __float2bfloat16(v.y),
                 __float2bfloat16(v.z), __float2bfloat16(v.w)};
    *(ushort4*)(dst + i4) = *(ushort4*)o;
}

// ---------------------------------------------------------------------------
// Fused QKV v2: one block per (row-tile, head) computes Q, K, V together.
// grid = (68, 12). Outputs: Q*QSCALE row-major; K/V pre-swizzled frag order.
// ---------------------------------------------------------------------------
__global__ __launch_bounds__(256, 4) void qkv_kernel(
    const bf16* __restrict__ xb, const bf16* __restrict__ wbase,
    const float* __restrict__ bq_p, const float* __restrict__ bq_d,
    const float* __restrict__ bv_p, const float* __restrict__ bv_d,
    bf16* __restrict__ Qb, bf16* __restrict__ Ksw, bf16* __restrict__ Vsw) {
    __shared__ bf16 As[64][32];
    __shared__ bf16 Bs[192][32];   // rows 0-63: wq, 64-127: wk, 128-191: wv

    const int tid = threadIdx.x;
    const int wave = tid >> 6, lane = tid & 63;
    const int quad = lane >> 4, l16 = lane & 15;
    const int bx = blockIdx.x;
    const int h = blockIdx.y;
    const int is_det = bx >= 66;
    const int row0 = is_det ? NP + (bx - 66) * 64 : bx * 64;
    const int Mlim = is_det ? NT : NP;
    const int col0 = h * 64;
    const size_t nw = (size_t)DMODEL * DMODEL;
    const bf16* W = wbase + (is_det ? 3 * nw : 0);

    const f32x4 z4 = {0.f, 0.f, 0.f, 0.f};
    f32x4 acc[4][3];
#pragma unroll
    for (int r4 = 0; r4 < 4; ++r4)
#pragma unroll
        for (int f = 0; f < 3; ++f) acc[r4][f] = z4;

    const int srow = tid >> 2;          // 0..63
    const int scol8 = (tid & 3) * 8;    // 0,8,16,24
    int a_r = row0 + srow;
    if (a_r >= Mlim) a_r = Mlim - 1;
    const bf16* ap = xb + (size_t)a_r * DMODEL + scol8;
    const bf16* bp = W + (size_t)(col0 + srow) * DMODEL + scol8;

    uint4 areg  = *(const uint4*)(ap);
    uint4 breg0 = *(const uint4*)(bp);
    uint4 breg1 = *(const uint4*)(bp + nw);
    uint4 breg2 = *(const uint4*)(bp + 2 * nw);

    for (int k0 = 0; k0 < DMODEL; k0 += 32) {
        __syncthreads();
        *(uint4*)(&As[srow][scol8]) = areg;
        *(uint4*)(&Bs[srow][scol8]) = breg0;
        *(uint4*)(&Bs[64 + srow][scol8]) = breg1;
        *(uint4*)(&Bs[128 + srow][scol8]) = breg2;
        if (k0 + 32 < DMODEL) {
            areg  = *(const uint4*)(ap + k0 + 32);
            breg0 = *(const uint4*)(bp + k0 + 32);
            breg1 = *(const uint4*)(bp + nw + k0 + 32);
            breg2 = *(const uint4*)(bp + 2 * nw + k0 + 32);
        }
        __asm__ volatile("s_waitcnt lgkmcnt(0)" ::: "memory");
        __builtin_amdgcn_s_barrier();   // prefetch vmcnt stays in flight
        __asm__ volatile("" ::: "memory");
        frag8 af[4], bfr[3];
#pragma unroll
        for (int r4 = 0; r4 < 4; ++r4)
            af[r4] = *(const frag8*)(&As[r4 * 16 + l16][quad * 8]);
#pragma unroll
        for (int f = 0; f < 3; ++f)
            bfr[f] = *(const frag8*)(&Bs[wave * 48 + f * 16 + l16][quad * 8]);
#pragma unroll
        for (int r4 = 0; r4 < 4; ++r4)
#pragma unroll
            for (int f = 0; f < 3; ++f)
                acc[r4][f] = __builtin_amdgcn_mfma_f32_16x16x32_bf16(af[r4], bfr[f], acc[r4][f], 0, 0, 0);
        __asm__ volatile("" ::: "memory");
    }

    // epilogue: wave w covers logical cols [w*48, w*48+48); 16-col group oc=3w+f
#pragma unroll
    for (int f = 0; f < 3; ++f) {
        const int oc = 3 * wave + f;          // 0..11
        const int opi = oc >> 2;              // 0=Q 1=K 2=V
        const int cin = (oc & 3) * 16 + l16;  // head-dim 0..63
        const int c = col0 + cin;             // global dim
        float bv = 0.f, scale = 1.f;
        if (opi == 0) { bv = (is_det ? bq_d : bq_p)[c]; scale = QSCALE; }
        else if (opi == 2) { bv = (is_det ? bv_d : bv_p)[c]; }
#pragma unroll
        for (int r4 = 0; r4 < 4; ++r4) {
#pragma unroll
            for (int j = 0; j < 4; ++j) {
                const int r = row0 + r4 * 16 + quad * 4 + j;
                if (r >= Mlim) continue;
                const bf16 val = __float2bfloat16((acc[r4][f][j] + bv) * scale);
                if (opi == 0) {
                    Qb[(size_t)r * DMODEL + c] = val;
                } else if (opi == 1) {
                    const int cc = r >> 6, tf = (r >> 4) & 3, ln = r & 15;
                    const int s = cin >> 5, qd = (cin >> 3) & 3, je = cin & 7;
                    Ksw[((size_t)(h * NCHUNK + cc) * 8 + tf * 2 + s) * FRAGSZ +
                        (qd * 16 + ln) * 8 + je] = val;
                } else {
                    const int t = cin >> 4, le = cin & 15;
                    const int cc = r >> 6, rr = r & 63;
                    const int sv = rr >> 5, qv = (rr >> 3) & 3, je = rr & 7;
                    Vsw[((size_t)(h * NCHUNK + cc) * 8 + t * 2 + sv) * FRAGSZ +
                        (qv * 16 + le) * 8 + je] = val;
                }
            }
        }
    }
}

// ---------------------------------------------------------------------------
// Flash attention v8.1: 32 q-rows per wave (128-row blocks); each K/V frag
// feeds 2 MFMAs. Packed f32x2->bf16x2 conversion (v_cvt_pk_bf16_f32) for the
// P tile cuts ~64 VALU ops/iter vs scalar converts. Barrier-free; frag-order
// global K/V; wave-private LDS P transpose; kv-split partials.
// ---------------------------------------------------------------------------
__global__ __launch_bounds__(256, 2) void attn_kernel(
    const bf16* __restrict__ Q, const bf16* __restrict__ Ksw,
    const bf16* __restrict__ Vsw, float* __restrict__ O_part,
    float* __restrict__ l_part, int cpb) {
    __shared__ unsigned short Ps[4][32][72];   // per-wave 32-row P tile

    const int tid = threadIdx.x;
    const int wave = tid >> 6, lane = tid & 63;
    const int quad = lane >> 4, l16 = lane & 15;
    const int h = blockIdx.y;
    const int z = blockIdx.z;
    const int qbase = blockIdx.x * 128;
    const int hoff = h * HD;
    const int c0 = z * cpb, c1 = c0 + cpb;

    frag8 ones;
#pragma unroll
    for (int j = 0; j < 8; ++j) ones[j] = (short)0x3F80;

    // Q fragments for 2 row-groups: rows qbase + wave*32 + g*16 + l16
    frag8 qf[2][2];
#pragma unroll
    for (int g = 0; g < 2; ++g) {
        int qr = qbase + wave * 32 + g * 16 + l16;
        if (qr >= NT) qr = NT - 1;
#pragma unroll
        for (int s = 0; s < 2; ++s)
            qf[g][s] = *(const frag8*)(Q + (size_t)qr * DMODEL + hoff + s * 32 + quad * 8);
    }

    const bf16* kb0 = Ksw + (size_t)h * NCHUNK * CHUNKSZ + lane * 8;
    const bf16* vb0 = Vsw + (size_t)h * NCHUNK * CHUNKSZ + lane * 8;

    const f32x4 z4 = {0.f, 0.f, 0.f, 0.f};
    f32x4 accO[2][4], accL[2];
#pragma unroll
    for (int g = 0; g < 2; ++g) {
        accL[g] = z4;
#pragma unroll
        for (int t = 0; t < 4; ++t) accO[g][t] = z4;
    }

    for (int c = c0; c < c1; ++c) {
        const bf16* kc = kb0 + (size_t)c * CHUNKSZ;
        const bf16* vc = vb0 + (size_t)c * CHUNKSZ;
        frag8 kf[8], vf[8];
#pragma unroll
        for (int f = 0; f < 8; ++f) {
            kf[f] = *(const frag8*)(kc + f * FRAGSZ);
            vf[f] = *(const frag8*)(vc + f * FRAGSZ);
        }

        // S = Q @ K^T for both row-groups (16 MFMA per 8 kf frags)
        f32x4 S[2][4];
#pragma unroll
        for (int g = 0; g < 2; ++g)
#pragma unroll
            for (int t = 0; t < 4; ++t) {
                f32x4 s0 = __builtin_amdgcn_mfma_f32_16x16x32_bf16(qf[g][0], kf[t * 2 + 0], z4, 0, 0, 0);
                S[g][t]  = __builtin_amdgcn_mfma_f32_16x16x32_bf16(qf[g][1], kf[t * 2 + 1], s0, 0, 0, 0);
            }
        if (c == NCHUNK - 1) {
            const int kbase = c * 64;
#pragma unroll
            for (int t = 0; t < 4; ++t)
                if (kbase + t * 16 + l16 >= NT)
#pragma unroll
                    for (int g = 0; g < 2; ++g)
                        S[g][t][0] = S[g][t][1] = S[g][t][2] = S[g][t][3] = -1e30f;
        }
        // p = exp2(s) -> wave-private LDS; packed pair conversion (rows j, j+1)
#pragma unroll
        for (int g = 0; g < 2; ++g)
#pragma unroll
            for (int t = 0; t < 4; ++t)
#pragma unroll
                for (int j = 0; j < 4; j += 2) {
                    float2 f2 = make_float2(__builtin_exp2f(S[g][t][j]),
                                            __builtin_exp2f(S[g][t][j + 1]));
                    __hip_bfloat162 b2 = __float22bfloat162_rn(f2);
                    unsigned int u = *(unsigned int*)&b2;
                    Ps[wave][g * 16 + quad * 4 + j][t * 16 + l16] = (unsigned short)u;
                    Ps[wave][g * 16 + quad * 4 + j + 1][t * 16 + l16] = (unsigned short)(u >> 16);
                }
        __asm__ volatile("" ::: "memory");   // same-wave DS in-order
        // O += P @ V ; l += P @ ones  (20 MFMA per 8 vf frags)
#pragma unroll
        for (int s = 0; s < 2; ++s)
#pragma unroll
            for (int g = 0; g < 2; ++g) {
                frag8 pf = *(const frag8*)(&Ps[wave][g * 16 + l16][s * 32 + quad * 8]);
                accL[g] = __builtin_amdgcn_mfma_f32_16x16x32_bf16(pf, ones, accL[g], 0, 0, 0);
#pragma unroll
                for (int t = 0; t < 4; ++t)
                    accO[g][t] = __builtin_amdgcn_mfma_f32_16x16x32_bf16(pf, vf[t * 2 + s], accO[g][t], 0, 0, 0);
            }
        __asm__ volatile("" ::: "memory");
    }

    // write fp32 partials
    float* Op = O_part + (size_t)z * NT * DMODEL;
#pragma unroll
    for (int g = 0; g < 2; ++g)
#pragma unroll
        for (int j = 0; j < 4; ++j) {
            const int r = qbase + wave * 32 + g * 16 + quad * 4 + j;
            if (r < NT) {
#pragma unroll
                for (int t = 0; t < 4; ++t)
                    Op[(size_t)r * DMODEL + hoff + t * 16 + l16] = accO[g][t][j];
                if (l16 == 0)
                    l_part[((size_t)z * NHEAD + h) * NTP + r] = accL[g][j];
            }
        }
}

// ---------------------------------------------------------------------------
// Reduce kv-splits + per-head normalize + LayerNorm. grid = (NT), 192 thr.
// Each thread owns 4 consecutive dims (float4 loads; same head per quad).
// ---------------------------------------------------------------------------
__global__ __launch_bounds__(192) void reduce_ln_kernel(
    const float* __restrict__ O_part, const float* __restrict__ l_part,
    const float* __restrict__ g, const float* __restrict__ b,
    bf16* __restrict__ out, int nsplit) {
    const int n = blockIdx.x;
    const int tid = threadIdx.x;
    const int d0 = tid * 4;
    const int hh = d0 >> 6;

    float4 o = make_float4(0.f, 0.f, 0.f, 0.f);
    float lv = 0.f;
    for (int s = 0; s < nsplit; ++s) {
        float4 v = *(const float4*)(O_part + ((size_t)s * NT + n) * DMODEL + d0);
        o.x += v.x; o.y += v.y; o.z += v.z; o.w += v.w;
        lv += l_part[((size_t)s * NHEAD + hh) * NTP + n];
    }
    const float inv_l = 1.0f / lv;
    float vals[4] = {o.x * inv_l, o.y * inv_l, o.z * inv_l, o.w * inv_l};

    float s = vals[0] + vals[1] + vals[2] + vals[3];
    float s2 = vals[0] * vals[0] + vals[1] * vals[1] + vals[2] * vals[2] + vals[3] * vals[3];
#pragma unroll
    for (int off = 1; off < 64; off <<= 1) {
        s += __shfl_xor(s, off);
        s2 += __shfl_xor(s2, off);
    }
    __shared__ float ss[3], ss2[3];
    const int wave = tid >> 6, lane = tid & 63;
    if (lane == 0) { ss[wave] = s; ss2[wave] = s2; }
    __syncthreads();
    s = ss[0] + ss[1] + ss[2];
    s2 = ss2[0] + ss2[1] + ss2[2];
    const float mu = s * (1.0f / 768.0f);
    float var = s2 * (1.0f / 768.0f) - mu * mu;
    const float inv = rsqrtf(var + LN_EPS);

    unsigned short pk[4];
#pragma unroll
    for (int i = 0; i < 4; ++i) {
        const int d = d0 + i;
        const float v = (vals[i] - mu) * inv * g[d] + b[d];
        bf16 bb = __float2bfloat16(v);
        pk[i] = *(unsigned short*)&bb;
    }
    *(ushort4*)(out + (size_t)n * DMODEL + d0) = *(ushort4*)pk;
}

// ---------------------------------------------------------------------------
// Output projection v2: 128-row blocks, region-select. grid = (34, 12).
// Wave owns 32 rows as 2 groups sharing B-frags: 8 MFMA per 6 ds_read_b128.
// fp32 out.
// ---------------------------------------------------------------------------
__global__ __launch_bounds__(256, 2) void out_kernel(
    const bf16* __restrict__ Lb, const bf16* __restrict__ wo,
    const float* __restrict__ bo_p, const float* __restrict__ bo_d,
    float* __restrict__ out) {
    __shared__ bf16 As[128][32];
    __shared__ bf16 Bs[64][32];

    const int tid = threadIdx.x;
    const int wave = tid >> 6, lane = tid & 63;
    const int quad = lane >> 4, l16 = lane & 15;
    const int bx = blockIdx.x;
    const int is_det = bx >= 33;
    const int row0 = is_det ? NP : bx * 128;
    const int Mlim = is_det ? NT : NP;
    const int col0 = blockIdx.y * 64;
    const size_t nw = (size_t)DMODEL * DMODEL;
    const bf16* B = wo + (is_det ? nw : 0);
    const float* bias = is_det ? bo_d : bo_p;

    const f32x4 z4 = {0.f, 0.f, 0.f, 0.f};
    f32x4 acc[2][4];
#pragma unroll
    for (int gg = 0; gg < 2; ++gg)
#pragma unroll
        for (int t = 0; t < 4; ++t) acc[gg][t] = z4;

    // staging: As 128x32 (2 uint4/thread, same row), Bs 64x32 (1 uint4/thread)
    const int arow = tid >> 1;              // 0..127
    const int acol = (tid & 1) * 16;        // 0 or 16
    int a_r = row0 + arow;
    if (a_r >= Mlim) a_r = Mlim - 1;
    const bf16* ap = Lb + (size_t)a_r * DMODEL + acol;
    const int brow = tid >> 2;              // 0..63
    const int bcol = (tid & 3) * 8;
    const bf16* bp = B + (size_t)(col0 + brow) * DMODEL + bcol;

    uint4 areg0 = *(const uint4*)(ap);
    uint4 areg1 = *(const uint4*)(ap + 8);
    uint4 breg  = *(const uint4*)(bp);

    for (int k0 = 0; k0 < DMODEL; k0 += 32) {
        __syncthreads();
        *(uint4*)(&As[arow][acol]) = areg0;
        *(uint4*)(&As[arow][acol + 8]) = areg1;
        *(uint4*)(&Bs[brow][bcol]) = breg;
        if (k0 + 32 < DMODEL) {
            areg0 = *(const uint4*)(ap + k0 + 32);
            areg1 = *(const uint4*)(ap + k0 + 40);
            breg  = *(const uint4*)(bp + k0 + 32);
        }
        __asm__ volatile("s_waitcnt lgkmcnt(0)" ::: "memory");
        __builtin_amdgcn_s_barrier();
        __asm__ volatile("" ::: "memory");
        frag8 af[2], bfq[4];
#pragma unroll
        for (int gg = 0; gg < 2; ++gg)
            af[gg] = *(const frag8*)(&As[wave * 32 + gg * 16 + l16][quad * 8]);
#pragma unroll
        for (int t = 0; t < 4; ++t)
            bfq[t] = *(const frag8*)(&Bs[t * 16 + l16][quad * 8]);
#pragma unroll
        for (int gg = 0; gg < 2; ++gg)
#pragma unroll
            for (int t = 0; t < 4; ++t)
                acc[gg][t] = __builtin_amdgcn_mfma_f32_16x16x32_bf16(af[gg], bfq[t], acc[gg][t], 0, 0, 0);
        __asm__ volatile("" ::: "memory");
    }

#pragma unroll
    for (int gg = 0; gg < 2; ++gg) {
        const int rbase = row0 + wave * 32 + gg * 16 + quad * 4;
#pragma unroll
        for (int t = 0; t < 4; ++t) {
            const int c = col0 + t * 16 + l16;
            const float bv = bias[c];
#pragma unroll
            for (int j = 0; j < 4; ++j) {
                const int r = rbase + j;
                if (r < Mlim) out[(size_t)r * DMODEL + c] = acc[gg][t][j] + bv;
            }
        }
    }
}

// ---------------------------------------------------------------------------
extern "C" void kernel_launch(void* const* d_in, const int* in_sizes, int n_in,
                              void* d_out, int out_size, void* d_ws, size_t ws_size,
                              hipStream_t stream) {
    const float* x    = (const float*)d_in[0];
    const float* wq_p = (const float*)d_in[1];
    const float* wk_p = (const float*)d_in[2];
    const float* wv_p = (const float*)d_in[3];
    const float* wq_d = (const float*)d_in[4];
    const float* wk_d = (const float*)d_in[5];
    const float* wv_d = (const float*)d_in[6];
    const float* bq_p = (const float*)d_in[7];
    const float* bv_p = (const float*)d_in[8];
    const float* bq_d = (const float*)d_in[9];
    const float* bv_d = (const float*)d_in[10];
    const float* ln_g = (const float*)d_in[11];
    const float* ln_b = (const float*)d_in[12];
    const float* wo_p = (const float*)d_in[13];
    const float* bo_p = (const float*)d_in[14];
    const float* wo_d = (const float*)d_in[15];
    const float* bo_d = (const float*)d_in[16];
    float* out = (float*)d_out;

    const size_t nx  = (size_t)NT * DMODEL;       // 3,303,168
    const size_t nsw = (size_t)NHEAD * NCHUNK * CHUNKSZ;  // 3,342,336
    const size_t nw  = (size_t)DMODEL * DMODEL;   // 589,824

    // fixed region
    char* ws = (char*)d_ws;
    bf16* xb   = (bf16*)ws; ws += nx * 2;         // reused as Lb after qkv
    bf16* wqkv = (bf16*)ws; ws += 6 * nw * 2;
    bf16* wob  = (bf16*)ws; ws += 2 * nw * 2;
    bf16* Qb   = (bf16*)ws; ws += nx * 2;
    bf16* Ksw  = (bf16*)ws; ws += nsw * 2;
    bf16* Vsw  = (bf16*)ws; ws += nsw * 2;
    const size_t fixed = (size_t)(ws - (char*)d_ws);

    // per-split region: O_part (fp32 NT x 768) + l_part (fp32 12 x NTP)
    const size_t per_split = nx * 4 + (size_t)NHEAD * NTP * 4;
    int nsplit = 1;
    if (ws_size >= fixed + 4 * per_split) nsplit = 4;
    else if (ws_size >= fixed + 2 * per_split) nsplit = 2;
    const int cpb = NCHUNK / nsplit;              // 68 divisible by 1/2/4

    float* O_part = (float*)ws;
    float* l_part = (float*)(ws + (size_t)nsplit * nx * 4);
    bf16* Lb = xb;   // xb dead after qkv_kernel

    const int total = (int)(nx + 8 * nw);
    cast_all_kernel<<<dim3((total / 4 + 255) / 256), dim3(256), 0, stream>>>(
        x, wq_p, wk_p, wv_p, wq_d, wk_d, wv_d, wo_p, wo_d, xb, (int)nx, (int)nw, total);

    qkv_kernel<<<dim3(68, 12), dim3(256), 0, stream>>>(
        xb, wqkv, bq_p, bq_d, bv_p, bv_d, Qb, Ksw, Vsw);

    attn_kernel<<<dim3(34, NHEAD, nsplit), dim3(256), 0, stream>>>(
        Qb, Ksw, Vsw, O_part, l_part, cpb);

    reduce_ln_kernel<<<dim3(NT), dim3(192), 0, stream>>>(
        O_part, l_part, ln_g, ln_b, Lb, nsplit);

    out_kernel<<<dim3(34, 12), dim3(256), 0, stream>>>(Lb, wob, bo_p, bo_d, out);
}